// Round 1
// baseline (1344.816 us; speedup 1.0000x reference)
//
#include <hip/hip_runtime.h>

#define T_TOK 2048
#define HDIM  2048
#define NEXP  64
#define FDIM  512
#define KSEL  8
#define CAP   320
#define F2    1024

typedef __attribute__((ext_vector_type(8))) short bf16x8;
typedef __attribute__((ext_vector_type(4))) float f32x4;

__device__ __forceinline__ unsigned int pkbf(float a, float b) {
  unsigned int ua = __builtin_bit_cast(unsigned int, a);
  unsigned int ub = __builtin_bit_cast(unsigned int, b);
  return ((ua + 0x8000u) >> 16) | ((ub + 0x8000u) & 0xFFFF0000u);
}
__device__ __forceinline__ unsigned short f2bf(float a) {
  unsigned int ua = __builtin_bit_cast(unsigned int, a);
  return (unsigned short)((ua + 0x8000u) >> 16);
}

// ---------------- x -> bf16 ----------------
__global__ void cvt_kernel(const float* __restrict__ x, unsigned short* __restrict__ xb) {
  int i = blockIdx.x * 256 + threadIdx.x;            // one float4 per thread
  float4 v = reinterpret_cast<const float4*>(x)[i];
  uint2 o;
  o.x = pkbf(v.x, v.y);
  o.y = pkbf(v.z, v.w);
  reinterpret_cast<uint2*>(xb)[i] = o;
}

// ---------------- router: logits (f64 acc) -> softmax -> top-8 ----------------
__global__ __launch_bounds__(256) void router_kernel(
    const float* __restrict__ x, const float* __restrict__ rw,
    int* __restrict__ topi, float* __restrict__ topv, float* __restrict__ probsum) {
  __shared__ float ps[64];
  int tid = threadIdx.x;
  int wv = tid >> 6, lane = tid & 63;
  if (tid < 64) ps[tid] = 0.f;
  __syncthreads();
  int t = blockIdx.x * 4 + wv;
  const float* xrow = x + (long)t * HDIM;
  const float* wcol = rw + lane;
  double acc = 0.0;
#pragma unroll 8
  for (int h = 0; h < HDIM; h++)
    acc += (double)xrow[h] * (double)wcol[h * 64];
  float logit = (float)acc;
  float mx = logit;
  for (int off = 32; off; off >>= 1) mx = fmaxf(mx, __shfl_xor(mx, off));
  float ex = expf(logit - mx);
  float sm = ex;
  for (int off = 32; off; off >>= 1) sm += __shfl_xor(sm, off);
  float prob = ex / sm;
  atomicAdd(&ps[lane], prob);
  float p = prob;
  for (int k = 0; k < 8; k++) {
    float bv = p; int bi = lane;
    for (int off = 32; off; off >>= 1) {
      float ov = __shfl_xor(bv, off); int oi = __shfl_xor(bi, off);
      if (ov > bv || (ov == bv && oi < bi)) { bv = ov; bi = oi; }
    }
    if (lane == k) { topv[t * 8 + k] = bv; topi[t * 8 + k] = bi; }
    if (lane == bi) p = -1.f;
  }
  __syncthreads();
  if (tid < 64) atomicAdd(&probsum[tid], ps[tid]);
}

// ---------------- dispatch: exact k-major cumsum ranks ----------------
__global__ void rank_kernel(const int* __restrict__ topi, int* __restrict__ lrank,
                            int* __restrict__ hist) {
  __shared__ int ear[256];
  __shared__ unsigned short lr[256];
  int b = blockIdx.x, tid = threadIdx.x;
  int i = b * 256 + tid;
  int t = i & (T_TOK - 1), k = i >> 11;
  ear[tid] = topi[t * 8 + k];
  __syncthreads();
  if (tid < 64) {
    int c = 0;
    for (int j = 0; j < 256; j++)
      if (ear[j] == tid) { lr[j] = (unsigned short)c; c++; }
    hist[b * 64 + tid] = c;
  }
  __syncthreads();
  lrank[i] = lr[tid];
}

__global__ void scan_kernel(const int* __restrict__ hist, int* __restrict__ basetab,
                            int* __restrict__ cnt, const float* __restrict__ probsum,
                            float* __restrict__ aux_out) {
  int e = threadIdx.x;  // 64 threads, 1 wave
  int run = 0;
  for (int b = 0; b < 64; b++) { basetab[b * 64 + e] = run; run += hist[b * 64 + e]; }
  cnt[e] = run;
  float v = (float)run * probsum[e];
  for (int off = 32; off; off >>= 1) v += __shfl_xor(v, off);
  if (e == 0) aux_out[0] = 64.0f * v / ((float)(KSEL * T_TOK) * (float)T_TOK);
}

__global__ void build_kernel(const int* __restrict__ topi, const float* __restrict__ topv,
                             const int* __restrict__ lrank, const int* __restrict__ basetab,
                             int* __restrict__ idx_tab, float* __restrict__ wt_tab) {
  int b = blockIdx.x, tid = threadIdx.x;
  int i = b * 256 + tid;
  int t = i & (T_TOK - 1), k = i >> 11;
  int e = topi[t * 8 + k];
  int slot = basetab[b * 64 + e] + lrank[i];
  if (slot < CAP) {
    idx_tab[e * CAP + slot] = t;
    wt_tab[e * CAP + slot] = topv[t * 8 + k];
  }
}

// ---------------- fused gate/up GEMM: h = relu(A@Bg)*(A@Bu)*w, bf16 out ----------------
template <int N, int KD, int LDA, bool GATHER, bool HASWT>
__global__ __launch_bounds__(256) void gemm_gate_up(
    const unsigned short* __restrict__ Ab, long aStride,
    const int* __restrict__ idx, int idxStride,
    const float* __restrict__ Bg_, const float* __restrict__ Bu_, long bStride,
    const float* __restrict__ wt_,
    unsigned short* __restrict__ H_, long hStride, int M) {
  __shared__ unsigned short As[128 * 40];
  __shared__ unsigned short Bgs[128 * 40];
  __shared__ unsigned short Bus[128 * 40];
  int z = blockIdx.z;
  const unsigned short* A = Ab + (long)z * aStride;
  const float* Bg = Bg_ + (long)z * bStride;
  const float* Bu = Bu_ + (long)z * bStride;
  const int* idxp = GATHER ? idx + (long)z * idxStride : nullptr;
  const float* wtp = HASWT ? wt_ + (long)z * idxStride : nullptr;
  unsigned short* Hout = H_ + (long)z * hStride;
  int mt = blockIdx.y, nt = blockIdx.x;
  int tid = threadIdx.x;

  int arow = tid >> 1;
  int aseg = (tid & 1) * 2;  // 8-elem units
  int arow_g = mt * 128 + arow;
  long asrc = -1;
  if (arow_g < M) {
    int s = GATHER ? idxp[arow_g] : arow_g;
    if (s >= 0) asrc = (long)s * LDA;
  }
  unsigned short* adst = &As[arow * 40 + aseg * 8];

  int nn = tid & 127;
  int kh = tid >> 7;
  const float* bgp = Bg + (long)(kh * 16) * N + (nt * 128 + nn);
  const float* bup = Bu + (long)(kh * 16) * N + (nt * 128 + nn);
  unsigned short* bgd = &Bgs[nn * 40 + kh * 16];
  unsigned short* bud = &Bus[nn * 40 + kh * 16];

  int lane = tid & 63, quad = lane >> 4, r = lane & 15;
  int wv = tid >> 6, wm = wv & 1, wn = wv >> 1;

  f32x4 accg[4][4] = {};
  f32x4 accu[4][4] = {};

  for (int k0 = 0; k0 < KD; k0 += 32) {
    uint4 a0 = {0, 0, 0, 0}, a1 = {0, 0, 0, 0};
    if (asrc >= 0) {
      const uint4* ap = reinterpret_cast<const uint4*>(A + asrc + k0 + aseg * 8);
      a0 = ap[0]; a1 = ap[1];
    }
    float tg[16], tu[16];
    const float* bg0 = bgp + (long)k0 * N;
    const float* bu0 = bup + (long)k0 * N;
#pragma unroll
    for (int j = 0; j < 16; j++) { tg[j] = bg0[j * N]; tu[j] = bu0[j * N]; }
    *reinterpret_cast<uint4*>(adst) = a0;
    *reinterpret_cast<uint4*>(adst + 8) = a1;
    uint4 g0, g1, u0, u1;
    g0.x = pkbf(tg[0], tg[1]);  g0.y = pkbf(tg[2], tg[3]);
    g0.z = pkbf(tg[4], tg[5]);  g0.w = pkbf(tg[6], tg[7]);
    g1.x = pkbf(tg[8], tg[9]);  g1.y = pkbf(tg[10], tg[11]);
    g1.z = pkbf(tg[12], tg[13]); g1.w = pkbf(tg[14], tg[15]);
    u0.x = pkbf(tu[0], tu[1]);  u0.y = pkbf(tu[2], tu[3]);
    u0.z = pkbf(tu[4], tu[5]);  u0.w = pkbf(tu[6], tu[7]);
    u1.x = pkbf(tu[8], tu[9]);  u1.y = pkbf(tu[10], tu[11]);
    u1.z = pkbf(tu[12], tu[13]); u1.w = pkbf(tu[14], tu[15]);
    *reinterpret_cast<uint4*>(bgd) = g0;
    *reinterpret_cast<uint4*>(bgd + 8) = g1;
    *reinterpret_cast<uint4*>(bud) = u0;
    *reinterpret_cast<uint4*>(bud + 8) = u1;
    __syncthreads();
    bf16x8 af[4], bgf[4], buf2[4];
#pragma unroll
    for (int bm = 0; bm < 4; bm++)
      af[bm] = *reinterpret_cast<const bf16x8*>(&As[(wm * 64 + bm * 16 + r) * 40 + quad * 8]);
#pragma unroll
    for (int bn = 0; bn < 4; bn++) {
      bgf[bn] = *reinterpret_cast<const bf16x8*>(&Bgs[(wn * 64 + bn * 16 + r) * 40 + quad * 8]);
      buf2[bn] = *reinterpret_cast<const bf16x8*>(&Bus[(wn * 64 + bn * 16 + r) * 40 + quad * 8]);
    }
#pragma unroll
    for (int bm = 0; bm < 4; bm++)
#pragma unroll
      for (int bn = 0; bn < 4; bn++) {
        accg[bm][bn] = __builtin_amdgcn_mfma_f32_16x16x32_bf16(af[bm], bgf[bn], accg[bm][bn], 0, 0, 0);
        accu[bm][bn] = __builtin_amdgcn_mfma_f32_16x16x32_bf16(af[bm], buf2[bn], accu[bm][bn], 0, 0, 0);
      }
    __syncthreads();
  }
#pragma unroll
  for (int bm = 0; bm < 4; bm++)
#pragma unroll
    for (int i = 0; i < 4; i++) {
      int m = mt * 128 + wm * 64 + bm * 16 + quad * 4 + i;
      if (m < M) {
        float w = HASWT ? wtp[m] : 1.0f;
#pragma unroll
        for (int bn = 0; bn < 4; bn++) {
          int n = nt * 128 + wn * 64 + bn * 16 + r;
          float g = accg[bm][bn][i];
          float u = accu[bm][bn][i];
          float h = (g > 0.f ? g : 0.f) * u * w;
          Hout[(long)m * N + n] = f2bf(h);
        }
      }
    }
}

// ---------------- down GEMM + scatter-add combine ----------------
template <int N, int KD, int LDA, bool SCATTER>
__global__ __launch_bounds__(256) void gemm_down(
    const unsigned short* __restrict__ Ab, long aStride,
    const float* __restrict__ B_, long bStride,
    const int* __restrict__ idx, int idxStride,
    float* __restrict__ out, int M) {
  __shared__ unsigned short As[128 * 40];
  __shared__ unsigned short Bs[128 * 40];
  int z = blockIdx.z;
  const unsigned short* A = Ab + (long)z * aStride;
  const float* B = B_ + (long)z * bStride;
  const int* idxp = SCATTER ? idx + (long)z * idxStride : nullptr;
  int mt = blockIdx.y, nt = blockIdx.x;
  int tid = threadIdx.x;

  int arow = tid >> 1;
  int aseg = (tid & 1) * 2;
  int arow_g = mt * 128 + arow;
  long asrc = (arow_g < M) ? (long)arow_g * LDA : -1;
  unsigned short* adst = &As[arow * 40 + aseg * 8];

  int nn = tid & 127;
  int kh = tid >> 7;
  const float* bp = B + (long)(kh * 16) * N + (nt * 128 + nn);
  unsigned short* bd = &Bs[nn * 40 + kh * 16];

  int lane = tid & 63, quad = lane >> 4, r = lane & 15;
  int wv = tid >> 6, wm = wv & 1, wn = wv >> 1;

  f32x4 acc[4][4] = {};

  for (int k0 = 0; k0 < KD; k0 += 32) {
    uint4 a0 = {0, 0, 0, 0}, a1 = {0, 0, 0, 0};
    if (asrc >= 0) {
      const uint4* ap = reinterpret_cast<const uint4*>(A + asrc + k0 + aseg * 8);
      a0 = ap[0]; a1 = ap[1];
    }
    float tb[16];
    const float* b0 = bp + (long)k0 * N;
#pragma unroll
    for (int j = 0; j < 16; j++) tb[j] = b0[j * N];
    *reinterpret_cast<uint4*>(adst) = a0;
    *reinterpret_cast<uint4*>(adst + 8) = a1;
    uint4 w0, w1;
    w0.x = pkbf(tb[0], tb[1]);  w0.y = pkbf(tb[2], tb[3]);
    w0.z = pkbf(tb[4], tb[5]);  w0.w = pkbf(tb[6], tb[7]);
    w1.x = pkbf(tb[8], tb[9]);  w1.y = pkbf(tb[10], tb[11]);
    w1.z = pkbf(tb[12], tb[13]); w1.w = pkbf(tb[14], tb[15]);
    *reinterpret_cast<uint4*>(bd) = w0;
    *reinterpret_cast<uint4*>(bd + 8) = w1;
    __syncthreads();
    bf16x8 af[4], bf[4];
#pragma unroll
    for (int bm = 0; bm < 4; bm++)
      af[bm] = *reinterpret_cast<const bf16x8*>(&As[(wm * 64 + bm * 16 + r) * 40 + quad * 8]);
#pragma unroll
    for (int bn = 0; bn < 4; bn++)
      bf[bn] = *reinterpret_cast<const bf16x8*>(&Bs[(wn * 64 + bn * 16 + r) * 40 + quad * 8]);
#pragma unroll
    for (int bm = 0; bm < 4; bm++)
#pragma unroll
      for (int bn = 0; bn < 4; bn++)
        acc[bm][bn] = __builtin_amdgcn_mfma_f32_16x16x32_bf16(af[bm], bf[bn], acc[bm][bn], 0, 0, 0);
    __syncthreads();
  }
#pragma unroll
  for (int bm = 0; bm < 4; bm++)
#pragma unroll
    for (int i = 0; i < 4; i++) {
      int m = mt * 128 + wm * 64 + bm * 16 + quad * 4 + i;
      if (m < M) {
        int tok = SCATTER ? idxp[m] : m;
        if (tok >= 0) {
          float* orow = out + (long)tok * HDIM;
#pragma unroll
          for (int bn = 0; bn < 4; bn++) {
            int n = nt * 128 + wn * 64 + bn * 16 + r;
            atomicAdd(orow + n, acc[bm][bn][i]);
          }
        }
      }
    }
}

extern "C" void kernel_launch(void* const* d_in, const int* in_sizes, int n_in,
                              void* d_out, int out_size, void* d_ws, size_t ws_size,
                              hipStream_t stream) {
  const float* x   = (const float*)d_in[0];
  const float* rw  = (const float*)d_in[1];
  const float* wg  = (const float*)d_in[2];
  const float* wu  = (const float*)d_in[3];
  const float* wd  = (const float*)d_in[4];
  const float* swg = (const float*)d_in[5];
  const float* swu = (const float*)d_in[6];
  const float* swd = (const float*)d_in[7];
  float* out = (float*)d_out;

  char* ws = (char*)d_ws;
  size_t off = 0;
  auto alloc = [&](size_t bytes) -> char* {
    char* p = ws + off;
    off = (off + bytes + 255) & ~(size_t)255;
    return p;
  };
  unsigned short* xbf   = (unsigned short*)alloc((size_t)T_TOK * HDIM * 2);
  unsigned short* hbuf  = (unsigned short*)alloc((size_t)NEXP * CAP * FDIM * 2);
  unsigned short* hsbuf = (unsigned short*)alloc((size_t)2 * T_TOK * F2 * 2);
  int*   topi    = (int*)alloc(T_TOK * KSEL * 4);
  float* topv    = (float*)alloc(T_TOK * KSEL * 4);
  int*   lrank   = (int*)alloc(T_TOK * KSEL * 4);
  int*   hist    = (int*)alloc(64 * 64 * 4);
  int*   basetab = (int*)alloc(64 * 64 * 4);
  int*   cnt     = (int*)alloc(64 * 4);
  float* probsum = (float*)alloc(64 * 4);
  int*   idx_tab = (int*)alloc(NEXP * CAP * 4);
  float* wt_tab  = (float*)alloc(NEXP * CAP * 4);

  hipMemsetAsync(out, 0, (size_t)T_TOK * HDIM * 4, stream);
  hipMemsetAsync(probsum, 0, 64 * 4, stream);
  hipMemsetAsync(idx_tab, 0xFF, NEXP * CAP * 4, stream);
  hipMemsetAsync(wt_tab, 0, NEXP * CAP * 4, stream);

  cvt_kernel<<<T_TOK * HDIM / 4 / 256, 256, 0, stream>>>(x, xbf);
  router_kernel<<<T_TOK / 4, 256, 0, stream>>>(x, rw, topi, topv, probsum);
  rank_kernel<<<64, 256, 0, stream>>>(topi, lrank, hist);
  scan_kernel<<<1, 64, 0, stream>>>(hist, basetab, cnt, probsum, out + (size_t)T_TOK * HDIM);
  build_kernel<<<64, 256, 0, stream>>>(topi, topv, lrank, basetab, idx_tab, wt_tab);

  // routed experts: gate/up  [320 x 512] = gather(x) @ wg/wu, weight folded
  gemm_gate_up<FDIM, HDIM, HDIM, true, true><<<dim3(FDIM / 128, (CAP + 127) / 128, NEXP), 256, 0, stream>>>(
      xbf, 0L, idx_tab, CAP, wg, wu, (long)HDIM * FDIM, wt_tab, hbuf, (long)CAP * FDIM, CAP);
  // shared experts: gate/up  [2048 x 1024]
  gemm_gate_up<F2, HDIM, HDIM, false, false><<<dim3(F2 / 128, T_TOK / 128, 2), 256, 0, stream>>>(
      xbf, 0L, nullptr, 0, swg, swu, (long)HDIM * F2, nullptr, hsbuf, (long)T_TOK * F2, T_TOK);
  // routed down + scatter combine  [320 x 2048]
  gemm_down<HDIM, FDIM, FDIM, true><<<dim3(HDIM / 128, (CAP + 127) / 128, NEXP), 256, 0, stream>>>(
      hbuf, (long)CAP * FDIM, wd, (long)FDIM * HDIM, idx_tab, CAP, out, CAP);
  // shared down + add  [2048 x 2048]
  gemm_down<HDIM, F2, F2, false><<<dim3(HDIM / 128, T_TOK / 128, 2), 256, 0, stream>>>(
      hsbuf, (long)T_TOK * F2, swd, (long)F2 * HDIM, nullptr, 0, out, T_TOK);
}

// Round 2
// 1336.769 us; speedup vs baseline: 1.0060x; 1.0060x over previous
//
#include <hip/hip_runtime.h>

#define T_TOK 2048
#define HDIM  2048
#define NEXP  64
#define FDIM  512
#define KSEL  8
#define CAP   320
#define F2    1024

typedef __attribute__((ext_vector_type(8))) short bf16x8;
typedef __attribute__((ext_vector_type(4))) float f32x4;

__device__ __forceinline__ unsigned int pkbf(float a, float b) {
  unsigned int ua = __builtin_bit_cast(unsigned int, a);
  unsigned int ub = __builtin_bit_cast(unsigned int, b);
  return ((ua + 0x8000u) >> 16) | ((ub + 0x8000u) & 0xFFFF0000u);
}
__device__ __forceinline__ unsigned short f2bf(float a) {
  unsigned int ua = __builtin_bit_cast(unsigned int, a);
  return (unsigned short)((ua + 0x8000u) >> 16);
}

// ---------------- x -> bf16 ----------------
__global__ void cvt_kernel(const float* __restrict__ x, unsigned short* __restrict__ xb) {
  int i = blockIdx.x * 256 + threadIdx.x;
  float4 v = reinterpret_cast<const float4*>(x)[i];
  uint2 o;
  o.x = pkbf(v.x, v.y);
  o.y = pkbf(v.z, v.w);
  reinterpret_cast<uint2*>(xb)[i] = o;
}

// ---------------- router: logits (f64 acc) -> softmax -> top-8 ----------------
__global__ __launch_bounds__(256) void router_kernel(
    const float* __restrict__ x, const float* __restrict__ rw,
    int* __restrict__ topi, float* __restrict__ topv, float* __restrict__ probsum) {
  __shared__ float ps[64];
  int tid = threadIdx.x;
  int wv = tid >> 6, lane = tid & 63;
  if (tid < 64) ps[tid] = 0.f;
  __syncthreads();
  int t = blockIdx.x * 4 + wv;
  const float* xrow = x + (long)t * HDIM;
  const float* wcol = rw + lane;
  double acc = 0.0;
#pragma unroll 8
  for (int h = 0; h < HDIM; h++)
    acc += (double)xrow[h] * (double)wcol[h * 64];
  float logit = (float)acc;
  float mx = logit;
  for (int off = 32; off; off >>= 1) mx = fmaxf(mx, __shfl_xor(mx, off));
  float ex = expf(logit - mx);
  float sm = ex;
  for (int off = 32; off; off >>= 1) sm += __shfl_xor(sm, off);
  float prob = ex / sm;
  atomicAdd(&ps[lane], prob);
  float p = prob;
  for (int k = 0; k < 8; k++) {
    float bv = p; int bi = lane;
    for (int off = 32; off; off >>= 1) {
      float ov = __shfl_xor(bv, off); int oi = __shfl_xor(bi, off);
      if (ov > bv || (ov == bv && oi < bi)) { bv = ov; bi = oi; }
    }
    if (lane == k) { topv[t * 8 + k] = bv; topi[t * 8 + k] = bi; }
    if (lane == bi) p = -1.f;
  }
  __syncthreads();
  if (tid < 64) atomicAdd(&probsum[tid], ps[tid]);
}

// ---------------- dispatch: exact k-major cumsum ranks ----------------
__global__ void rank_kernel(const int* __restrict__ topi, int* __restrict__ lrank,
                            int* __restrict__ hist) {
  __shared__ int ear[256];
  __shared__ unsigned short lr[256];
  int b = blockIdx.x, tid = threadIdx.x;
  int i = b * 256 + tid;
  int t = i & (T_TOK - 1), k = i >> 11;
  ear[tid] = topi[t * 8 + k];
  __syncthreads();
  if (tid < 64) {
    int c = 0;
    for (int j = 0; j < 256; j++)
      if (ear[j] == tid) { lr[j] = (unsigned short)c; c++; }
    hist[b * 64 + tid] = c;
  }
  __syncthreads();
  lrank[i] = lr[tid];
}

__global__ void scan_kernel(const int* __restrict__ hist, int* __restrict__ basetab,
                            int* __restrict__ cnt, const float* __restrict__ probsum,
                            float* __restrict__ aux_out) {
  int e = threadIdx.x;
  int run = 0;
  for (int b = 0; b < 64; b++) { basetab[b * 64 + e] = run; run += hist[b * 64 + e]; }
  cnt[e] = run;
  float v = (float)run * probsum[e];
  for (int off = 32; off; off >>= 1) v += __shfl_xor(v, off);
  if (e == 0) aux_out[0] = 64.0f * v / ((float)(KSEL * T_TOK) * (float)T_TOK);
}

__global__ void build_kernel(const int* __restrict__ topi, const float* __restrict__ topv,
                             const int* __restrict__ lrank, const int* __restrict__ basetab,
                             int* __restrict__ idx_tab, float* __restrict__ wt_tab) {
  int b = blockIdx.x, tid = threadIdx.x;
  int i = b * 256 + tid;
  int t = i & (T_TOK - 1), k = i >> 11;
  int e = topi[t * 8 + k];
  int slot = basetab[b * 64 + e] + lrank[i];
  if (slot < CAP) {
    idx_tab[e * CAP + slot] = t;
    wt_tab[e * CAP + slot] = topv[t * 8 + k];
  }
}

// ================= pipelined GEMMs: 64x128 tile, BK=32, double LDS buffer =================
// LDS row stride 34 shorts (17 words, odd -> conflict-free fragment reads)

struct RawGU { uint4 a; float2 g[8]; float2 u[8]; };
struct RawD  { uint4 a; float2 b[8]; };

// fused gate/up: h = relu(A@Bg)*(A@Bu)*w, bf16 out. A: bf16 [rows,2048]; Bg/Bu f32 [2048,N]
template <int N, bool GATHER, bool HASWT>
__global__ __launch_bounds__(256) void gemm_gate_up(
    const unsigned short* __restrict__ Ab,
    const int* __restrict__ idx, int idxStride,
    const float* __restrict__ Bg_, const float* __restrict__ Bu_, long bStride,
    const float* __restrict__ wt_,
    unsigned short* __restrict__ H_, long hStride, int ldH) {
  constexpr int SA = 34;
  __shared__ unsigned short As[2][64 * SA];
  __shared__ unsigned short Bgs[2][128 * SA];
  __shared__ unsigned short Bus[2][128 * SA];
  const int z = blockIdx.z;
  const int mt = blockIdx.y, nt = blockIdx.x;
  const int tid = threadIdx.x;
  const float* Bg = Bg_ + (long)z * bStride + nt * 128;
  const float* Bu = Bu_ + (long)z * bStride + nt * 128;
  const int* idxp = GATHER ? idx + (long)z * idxStride : nullptr;
  const float* wtp = HASWT ? wt_ + (long)z * idxStride : nullptr;
  unsigned short* Hout = H_ + (long)z * hStride;

  // staging roles
  const int arow = tid >> 2, achk = tid & 3;
  const int mg_a = mt * 64 + arow;
  long asrc = -1;
  {
    int s = GATHER ? idxp[mg_a] : mg_a;
    if (s >= 0) asrc = (long)s * HDIM + achk * 8;
  }
  const int n2 = (tid & 63) * 2, kh = tid >> 6;
  const float* bgp = Bg + (long)(kh * 8) * N + n2;
  const float* bup = Bu + (long)(kh * 8) * N + n2;

  // compute roles
  const int lane = tid & 63, r = lane & 15, quad = lane >> 4;
  const int wv = tid >> 6, wm = wv & 1, wn = wv >> 1;

  f32x4 accg[2][4] = {}, accu[2][4] = {};
  RawGU c0, c1;

  auto loadT = [&](int k0, RawGU& rg) {
    uint4 a = {0, 0, 0, 0};
    if (asrc >= 0) a = *reinterpret_cast<const uint4*>(Ab + asrc + k0);
    rg.a = a;
    const float* pg = bgp + (long)k0 * N;
    const float* pu = bup + (long)k0 * N;
#pragma unroll
    for (int j = 0; j < 8; j++) {
      rg.g[j] = *reinterpret_cast<const float2*>(pg + (long)j * N);
      rg.u[j] = *reinterpret_cast<const float2*>(pu + (long)j * N);
    }
  };
  auto storeT = [&](const RawGU& rg, int buf) {
    *reinterpret_cast<uint4*>(&As[buf][arow * SA + achk * 8]) = rg.a;
    uint4 w;
    w.x = pkbf(rg.g[0].x, rg.g[1].x); w.y = pkbf(rg.g[2].x, rg.g[3].x);
    w.z = pkbf(rg.g[4].x, rg.g[5].x); w.w = pkbf(rg.g[6].x, rg.g[7].x);
    *reinterpret_cast<uint4*>(&Bgs[buf][n2 * SA + kh * 8]) = w;
    w.x = pkbf(rg.g[0].y, rg.g[1].y); w.y = pkbf(rg.g[2].y, rg.g[3].y);
    w.z = pkbf(rg.g[4].y, rg.g[5].y); w.w = pkbf(rg.g[6].y, rg.g[7].y);
    *reinterpret_cast<uint4*>(&Bgs[buf][(n2 + 1) * SA + kh * 8]) = w;
    w.x = pkbf(rg.u[0].x, rg.u[1].x); w.y = pkbf(rg.u[2].x, rg.u[3].x);
    w.z = pkbf(rg.u[4].x, rg.u[5].x); w.w = pkbf(rg.u[6].x, rg.u[7].x);
    *reinterpret_cast<uint4*>(&Bus[buf][n2 * SA + kh * 8]) = w;
    w.x = pkbf(rg.u[0].y, rg.u[1].y); w.y = pkbf(rg.u[2].y, rg.u[3].y);
    w.z = pkbf(rg.u[4].y, rg.u[5].y); w.w = pkbf(rg.u[6].y, rg.u[7].y);
    *reinterpret_cast<uint4*>(&Bus[buf][(n2 + 1) * SA + kh * 8]) = w;
  };
  auto compT = [&](int buf) {
    bf16x8 a0 = *reinterpret_cast<const bf16x8*>(&As[buf][(wm * 32 + r) * SA + quad * 8]);
    bf16x8 a1 = *reinterpret_cast<const bf16x8*>(&As[buf][(wm * 32 + 16 + r) * SA + quad * 8]);
#pragma unroll
    for (int bn = 0; bn < 4; bn++) {
      bf16x8 b = *reinterpret_cast<const bf16x8*>(&Bgs[buf][(wn * 64 + bn * 16 + r) * SA + quad * 8]);
      accg[0][bn] = __builtin_amdgcn_mfma_f32_16x16x32_bf16(a0, b, accg[0][bn], 0, 0, 0);
      accg[1][bn] = __builtin_amdgcn_mfma_f32_16x16x32_bf16(a1, b, accg[1][bn], 0, 0, 0);
    }
#pragma unroll
    for (int bn = 0; bn < 4; bn++) {
      bf16x8 b = *reinterpret_cast<const bf16x8*>(&Bus[buf][(wn * 64 + bn * 16 + r) * SA + quad * 8]);
      accu[0][bn] = __builtin_amdgcn_mfma_f32_16x16x32_bf16(a0, b, accu[0][bn], 0, 0, 0);
      accu[1][bn] = __builtin_amdgcn_mfma_f32_16x16x32_bf16(a1, b, accu[1][bn], 0, 0, 0);
    }
  };

  loadT(0, c0);
  storeT(c0, 0);
  loadT(32, c0);
  __syncthreads();
  constexpr int NK = HDIM / 32;  // 64
#pragma unroll 1
  for (int kt = 0; kt < NK; kt += 2) {
    if (kt + 2 < NK) loadT((kt + 2) * 32, c1);
    compT(0);
    storeT(c0, 1);
    __syncthreads();
    if (kt + 3 < NK) loadT((kt + 3) * 32, c0);
    compT(1);
    if (kt + 2 < NK) storeT(c1, 0);
    __syncthreads();
  }

#pragma unroll
  for (int bm = 0; bm < 2; bm++)
#pragma unroll
    for (int i = 0; i < 4; i++) {
      int mg = mt * 64 + wm * 32 + bm * 16 + quad * 4 + i;
      float w = HASWT ? wtp[mg] : 1.0f;
#pragma unroll
      for (int bn = 0; bn < 4; bn++) {
        int n = nt * 128 + wn * 64 + bn * 16 + r;
        float g = accg[bm][bn][i], u = accu[bm][bn][i];
        Hout[(long)mg * ldH + n] = f2bf(fmaxf(g, 0.f) * u * w);
      }
    }
}

// down GEMM (N=2048): out += A @ B, scatter or direct
template <int KD, int LDA, bool SCATTER>
__global__ __launch_bounds__(256) void gemm_down(
    const unsigned short* __restrict__ Ab, long aStride,
    const float* __restrict__ B_, long bStride,
    const int* __restrict__ idx, int idxStride,
    float* __restrict__ out) {
  constexpr int SA = 34;
  constexpr int N = HDIM;
  __shared__ unsigned short As[2][64 * SA];
  __shared__ unsigned short Bs[2][128 * SA];
  const int z = blockIdx.z;
  const int mt = blockIdx.y, nt = blockIdx.x;
  const int tid = threadIdx.x;
  const unsigned short* A = Ab + (long)z * aStride;
  const float* B = B_ + (long)z * bStride + nt * 128;
  const int* idxp = SCATTER ? idx + (long)z * idxStride : nullptr;

  const int arow = tid >> 2, achk = tid & 3;
  const long asrc = (long)(mt * 64 + arow) * LDA + achk * 8;
  const int n2 = (tid & 63) * 2, kh = tid >> 6;
  const float* bp = B + (long)(kh * 8) * N + n2;

  const int lane = tid & 63, r = lane & 15, quad = lane >> 4;
  const int wv = tid >> 6, wm = wv & 1, wn = wv >> 1;

  f32x4 acc[2][4] = {};
  RawD c0, c1;

  auto loadT = [&](int k0, RawD& rg) {
    rg.a = *reinterpret_cast<const uint4*>(A + asrc + k0);
    const float* p = bp + (long)k0 * N;
#pragma unroll
    for (int j = 0; j < 8; j++)
      rg.b[j] = *reinterpret_cast<const float2*>(p + (long)j * N);
  };
  auto storeT = [&](const RawD& rg, int buf) {
    *reinterpret_cast<uint4*>(&As[buf][arow * SA + achk * 8]) = rg.a;
    uint4 w;
    w.x = pkbf(rg.b[0].x, rg.b[1].x); w.y = pkbf(rg.b[2].x, rg.b[3].x);
    w.z = pkbf(rg.b[4].x, rg.b[5].x); w.w = pkbf(rg.b[6].x, rg.b[7].x);
    *reinterpret_cast<uint4*>(&Bs[buf][n2 * SA + kh * 8]) = w;
    w.x = pkbf(rg.b[0].y, rg.b[1].y); w.y = pkbf(rg.b[2].y, rg.b[3].y);
    w.z = pkbf(rg.b[4].y, rg.b[5].y); w.w = pkbf(rg.b[6].y, rg.b[7].y);
    *reinterpret_cast<uint4*>(&Bs[buf][(n2 + 1) * SA + kh * 8]) = w;
  };
  auto compT = [&](int buf) {
    bf16x8 a0 = *reinterpret_cast<const bf16x8*>(&As[buf][(wm * 32 + r) * SA + quad * 8]);
    bf16x8 a1 = *reinterpret_cast<const bf16x8*>(&As[buf][(wm * 32 + 16 + r) * SA + quad * 8]);
#pragma unroll
    for (int bn = 0; bn < 4; bn++) {
      bf16x8 b = *reinterpret_cast<const bf16x8*>(&Bs[buf][(wn * 64 + bn * 16 + r) * SA + quad * 8]);
      acc[0][bn] = __builtin_amdgcn_mfma_f32_16x16x32_bf16(a0, b, acc[0][bn], 0, 0, 0);
      acc[1][bn] = __builtin_amdgcn_mfma_f32_16x16x32_bf16(a1, b, acc[1][bn], 0, 0, 0);
    }
  };

  loadT(0, c0);
  storeT(c0, 0);
  loadT(32, c0);
  __syncthreads();
  constexpr int NK = KD / 32;
#pragma unroll 1
  for (int kt = 0; kt < NK; kt += 2) {
    if (kt + 2 < NK) loadT((kt + 2) * 32, c1);
    compT(0);
    storeT(c0, 1);
    __syncthreads();
    if (kt + 3 < NK) loadT((kt + 3) * 32, c0);
    compT(1);
    if (kt + 2 < NK) storeT(c1, 0);
    __syncthreads();
  }

#pragma unroll
  for (int bm = 0; bm < 2; bm++)
#pragma unroll
    for (int i = 0; i < 4; i++) {
      int mg = mt * 64 + wm * 32 + bm * 16 + quad * 4 + i;
      if (SCATTER) {
        int tok = idxp[mg];
        if (tok >= 0) {
          float* orow = out + (long)tok * HDIM + nt * 128 + wn * 64 + r;
#pragma unroll
          for (int bn = 0; bn < 4; bn++) atomicAdd(orow + bn * 16, acc[bm][bn][i]);
        }
      } else {
        float* orow = out + (long)mg * HDIM + nt * 128 + wn * 64 + r;
#pragma unroll
        for (int bn = 0; bn < 4; bn++) orow[bn * 16] += acc[bm][bn][i];
      }
    }
}

extern "C" void kernel_launch(void* const* d_in, const int* in_sizes, int n_in,
                              void* d_out, int out_size, void* d_ws, size_t ws_size,
                              hipStream_t stream) {
  const float* x   = (const float*)d_in[0];
  const float* rw  = (const float*)d_in[1];
  const float* wg  = (const float*)d_in[2];
  const float* wu  = (const float*)d_in[3];
  const float* wd  = (const float*)d_in[4];
  const float* swg = (const float*)d_in[5];
  const float* swu = (const float*)d_in[6];
  const float* swd = (const float*)d_in[7];
  float* out = (float*)d_out;

  char* ws = (char*)d_ws;
  size_t off = 0;
  auto alloc = [&](size_t bytes) -> char* {
    char* p = ws + off;
    off = (off + bytes + 255) & ~(size_t)255;
    return p;
  };
  unsigned short* xbf   = (unsigned short*)alloc((size_t)T_TOK * HDIM * 2);
  unsigned short* hbuf  = (unsigned short*)alloc((size_t)NEXP * CAP * FDIM * 2);
  unsigned short* hsbuf = (unsigned short*)alloc((size_t)T_TOK * 2 * F2 * 2);  // [T, 2*F2] interleaved
  int*   topi    = (int*)alloc(T_TOK * KSEL * 4);
  float* topv    = (float*)alloc(T_TOK * KSEL * 4);
  int*   lrank   = (int*)alloc(T_TOK * KSEL * 4);
  int*   hist    = (int*)alloc(64 * 64 * 4);
  int*   basetab = (int*)alloc(64 * 64 * 4);
  int*   cnt     = (int*)alloc(64 * 4);
  float* probsum = (float*)alloc(64 * 4);
  int*   idx_tab = (int*)alloc(NEXP * CAP * 4);
  float* wt_tab  = (float*)alloc(NEXP * CAP * 4);

  hipMemsetAsync(out, 0, (size_t)T_TOK * HDIM * 4, stream);
  hipMemsetAsync(probsum, 0, 64 * 4, stream);
  hipMemsetAsync(idx_tab, 0xFF, NEXP * CAP * 4, stream);
  hipMemsetAsync(wt_tab, 0, NEXP * CAP * 4, stream);

  cvt_kernel<<<T_TOK * HDIM / 4 / 256, 256, 0, stream>>>(x, xbf);
  router_kernel<<<T_TOK / 4, 256, 0, stream>>>(x, rw, topi, topv, probsum);
  rank_kernel<<<64, 256, 0, stream>>>(topi, lrank, hist);
  scan_kernel<<<1, 64, 0, stream>>>(hist, basetab, cnt, probsum, out + (size_t)T_TOK * HDIM);
  build_kernel<<<64, 256, 0, stream>>>(topi, topv, lrank, basetab, idx_tab, wt_tab);

  // routed gate/up: [E] x [320,512] = gather(x) @ wg/wu (weight folded into h)
  gemm_gate_up<FDIM, true, true><<<dim3(FDIM / 128, CAP / 64, NEXP), 256, 0, stream>>>(
      xbf, idx_tab, CAP, wg, wu, (long)HDIM * FDIM, wt_tab, hbuf, (long)CAP * FDIM, FDIM);
  // shared gate/up: [2] x [2048,1024] -> interleaved hsbuf [T, 2048]
  gemm_gate_up<F2, false, false><<<dim3(F2 / 128, T_TOK / 64, 2), 256, 0, stream>>>(
      xbf, nullptr, 0, swg, swu, (long)HDIM * F2, nullptr, hsbuf, (long)F2, 2 * F2);
  // routed down + scatter-add combine: [E] x [320,2048] @ wd
  gemm_down<FDIM, FDIM, true><<<dim3(HDIM / 128, CAP / 64, NEXP), 256, 0, stream>>>(
      hbuf, (long)CAP * FDIM, wd, (long)FDIM * HDIM, idx_tab, CAP, out);
  // shared down (both experts merged, K=2048): out += hsbuf @ sw_d_flat
  gemm_down<2 * F2, 2 * F2, false><<<dim3(HDIM / 128, T_TOK / 64, 1), 256, 0, stream>>>(
      hsbuf, 0L, swd, 0L, nullptr, 0, out);
}